// Round 11
// baseline (2020.288 us; speedup 1.0000x reference)
//
#include <hip/hip_runtime.h>
#include <cstdint>
#include <cstddef>

#define S_DIM 12
#define N_NODE 50000
#define N_PAD 50048
#define N_P2 50176
#define D_IN 64
#define D_H 128
#define N_E 600000
#define K_TOT 576
#define N_COL 512
#define HID_P 80
#define N_HID 65
#define AXC 192

#define NB_PREP 1152
#define NB_DEG 2344
#define NB_SPMM 12500
#define NB_LN 782

typedef short bf16x8 __attribute__((ext_vector_type(8)));
typedef float f32x4 __attribute__((ext_vector_type(4)));

__device__ __forceinline__ float bf2f(unsigned short u){
  union { unsigned int i; float f; } v; v.i = ((unsigned int)u) << 16; return v.f;
}
__device__ __forceinline__ unsigned short f2bf(float f){
  union { float f; unsigned int i; } v; v.f = f;
  unsigned int x = v.i;
  return (unsigned short)((x + 0x7fffu + ((x >> 16) & 1u)) >> 16);
}
__device__ __forceinline__ float sigf(float x){ return 1.f/(1.f + __expf(-x)); }
__device__ __forceinline__ float ftanh(float x){
  x = fminf(fmaxf(x, -12.f), 12.f);
  float e = __expf(2.f*x);
  return (e - 1.f)/(e + 1.f);
}
__device__ __forceinline__ void gload16(const void* g, void* lds){
  __builtin_amdgcn_global_load_lds((const __attribute__((address_space(1))) unsigned int*)g,
                                   (__attribute__((address_space(3))) unsigned int*)lds, 16, 0, 0);
}
// accumulate 8 bf16 (uint4) * w
__device__ __forceinline__ void acc8(float* a, uint4 h, float w){
  unsigned int u[4] = {h.x, h.y, h.z, h.w};
#pragma unroll
  for (int i=0;i<4;++i){
    a[2*i]   += w * bf2f((unsigned short)(u[i] & 0xffffu));
    a[2*i+1] += w * bf2f((unsigned short)(u[i] >> 16));
  }
}

// ---------------- setup: weight pack + degree count ----------
__global__ void k_setup(const int* __restrict__ ei,
                        const float* __restrict__ Wx, const float* __restrict__ Wh,
                        const float* __restrict__ bx, const float* __restrict__ bh,
                        const float* __restrict__ bg, const float* __restrict__ W1,
                        const float* __restrict__ b1, const float* __restrict__ W2,
                        unsigned short* __restrict__ Bct, float* __restrict__ btot,
                        unsigned short* __restrict__ W1t, float* __restrict__ b1p,
                        float* __restrict__ W2p,
                        int* __restrict__ dsrc, int* __restrict__ ddst)
{
  int bb = blockIdx.x, tid = threadIdx.x;
  if (bb < NB_PREP){
    int idx = bb*256 + tid;
    if (idx < N_COL*K_TOT){
      int cc = idx / K_TOT, k = idx - cc*K_TOT;
      int g = (cc>>4)&3, d = (cc&15) + ((cc>>6)<<4);
      float v;
      if (k < 384){
        int kt = k >> 7, j = k & 127;
        const float* Wg = Wh + (size_t)g*3*128*128;
        if (kt == 0)      v = Wg[(size_t)j*128 + d] - Wg[(size_t)(256+j)*128 + d];
        else if (kt == 1) v = Wg[(size_t)(128+j)*128 + d];
        else              v = 2.f*Wg[(size_t)(256+j)*128 + d];
      } else {
        int kk = k - 384; int kt = kk >> 6, j = kk & 63;
        const float* Wg = Wx + (size_t)g*3*64*128;
        if (kt == 0)      v = Wg[(size_t)j*128 + d] - Wg[(size_t)(128+j)*128 + d];
        else if (kt == 1) v = Wg[(size_t)(64+j)*128 + d];
        else              v = 2.f*Wg[(size_t)(128+j)*128 + d];
      }
      Bct[(size_t)cc*K_TOT + k] = f2bf(v);
    }
    if (idx < N_COL) btot[idx] = bx[idx] + bh[idx] + bg[idx];
    if (idx < HID_P*D_H){ int c = idx >> 7, k = idx & 127;
      W1t[idx] = (c < N_HID) ? f2bf(W1[k*N_HID + c]) : (unsigned short)0; }
    if (idx < HID_P) b1p[idx] = (idx < N_HID) ? b1[idx] : 0.f;
    if (idx < HID_P*2){ int c = idx >> 1, j = idx & 1; W2p[idx] = (c < N_HID) ? W2[c*2 + j] : 0.f; }
  } else {
    int e = (bb - NB_PREP)*256 + tid;
    if (e < N_E){
      atomicAdd(&dsrc[ei[e]], 1);
      atomicAdd(&ddst[ei[N_E + e]], 1);
    }
  }
}

// ---------------- x conversion via LDS transpose: 32 nodes/block ----------------
#define XP_STR 2056
__global__ __launch_bounds__(256,3) void k_xprep(const float* __restrict__ H,
                        unsigned short* __restrict__ Xtr, unsigned short* __restrict__ Axt)
{
  __shared__ unsigned short xls[12*XP_STR];
  int bb = blockIdx.x, tid = threadIdx.x;
  int n0 = bb*32;
  int nn = tid >> 3;
  int d  = (tid & 7)*8;
  int gn = n0 + nn;
#pragma unroll
  for (int t=0;t<12;++t){
    unsigned short u[8];
    if (gn < N_NODE){
      const float* hp = H + ((size_t)t*N_NODE + gn)*64 + d;
      float4 a = *(const float4*)hp;
      float4 b = *(const float4*)(hp+4);
      u[0]=f2bf(a.x); u[1]=f2bf(a.y); u[2]=f2bf(a.z); u[3]=f2bf(a.w);
      u[4]=f2bf(b.x); u[5]=f2bf(b.y); u[6]=f2bf(b.z); u[7]=f2bf(b.w);
    } else {
#pragma unroll
      for (int i=0;i<8;++i) u[i]=0;
    }
    *(int4*)(xls + t*XP_STR + nn*64 + d) = *(const int4*)u;
    *(int4*)(Axt + ((size_t)t*N_PAD + gn)*AXC + d) = *(const int4*)u;
    if (gn >= N_NODE){
      *(int4*)(Axt + ((size_t)t*N_PAD + gn)*AXC + 64 + d)  = *(const int4*)u;
      *(int4*)(Axt + ((size_t)t*N_PAD + gn)*AXC + 128 + d) = *(const int4*)u;
    }
  }
  __syncthreads();
#pragma unroll
  for (int rep=0; rep<8; ++rep){
    int cIdx = rep*256 + tid;
    int n = cIdx >> 6, dd = cIdx & 63;
    unsigned int w0[3], w1[3];
#pragma unroll
    for (int i=0;i<3;++i){
      unsigned short a0 = xls[(2*i  )*XP_STR + n*64 + dd];
      unsigned short a1 = xls[(2*i+1)*XP_STR + n*64 + dd];
      unsigned short b0 = xls[(6+2*i)*XP_STR + n*64 + dd];
      unsigned short b1 = xls[(7+2*i)*XP_STR + n*64 + dd];
      w0[i] = (unsigned int)a0 | ((unsigned int)a1<<16);
      w1[i] = (unsigned int)b0 | ((unsigned int)b1<<16);
    }
    size_t cell = ((size_t)(n0+n)*64 + dd)*6;
    unsigned int* p0 = (unsigned int*)(Xtr + cell);
    unsigned int* p1 = (unsigned int*)(Xtr + (size_t)N_PAD*384 + cell);
    p0[0]=w0[0]; p0[1]=w0[1]; p0[2]=w0[2];
    p1[0]=w1[0]; p1[1]=w1[1]; p1[2]=w1[2];
  }
}

// ---------------- scans + csr ----------------
__global__ void k_scan1d(const int* __restrict__ in, int* __restrict__ outp, int* __restrict__ part,
                         const int* __restrict__ dsrc, float* __restrict__ dinv){
  __shared__ int sm[256];
  int tid = threadIdx.x;
  int i = blockIdx.x*256 + tid;
  dinv[i] = (dsrc[i] > 0) ? rsqrtf((float)dsrc[i]) : 0.f;
  int v = in[i];
  int x = v;
  sm[tid] = x; __syncthreads();
  for (int off=1; off<256; off<<=1){
    int y = (tid >= off) ? sm[tid-off] : 0;
    __syncthreads();
    x += y; sm[tid] = x; __syncthreads();
  }
  outp[i] = x - v;
  if (tid == 255) part[blockIdx.x] = x;
}
__global__ void k_scan3f(const int* __restrict__ outp, const int* __restrict__ part,
                         int* __restrict__ offs){
  __shared__ int sm[256];
  int tid = threadIdx.x;
  int v = (tid < N_P2/256) ? part[tid] : 0;
  int x = v; sm[tid] = x; __syncthreads();
  for (int off=1; off<256; off<<=1){
    int y = (tid >= off) ? sm[tid-off] : 0;
    __syncthreads();
    x += y; sm[tid] = x; __syncthreads();
  }
  int pref = (blockIdx.x > 0) ? sm[blockIdx.x - 1] : 0;
  int i = blockIdx.x*256 + tid;
  offs[i] = outp[i] + pref;
}
__global__ void k_csr(const int* __restrict__ ei, const float* __restrict__ dinv,
                      const int* __restrict__ offs, int* __restrict__ cursor,
                      int2* __restrict__ cedge){
  int e = blockIdx.x*256 + threadIdx.x;
  if (e < N_E){
    int s = ei[e], d = ei[N_E + e];
    int pos = atomicAdd(&cursor[d], 1);
    float w = -dinv[s]*dinv[d];
    cedge[offs[d] + pos] = make_int2(s, __float_as_int(w));
  }
}

// ---------------- x-side spmm bodies: gather dwords [D0, D0+ND) of packed cells ----
// Half-local dword i holds time planes (2i, 2i+1) of that half.
template<int D0, int ND>
__device__ __forceinline__ void xsp1_body(const unsigned short* __restrict__ Xh,
    unsigned short* __restrict__ AxtH, unsigned short* __restrict__ Uh,
    int n, int l, const int* __restrict__ offs, const int2* __restrict__ cedge)
{
  int beg = offs[n], end = offs[n+1];
  int ce = end - 1;
  float a[2*ND];
#pragma unroll
  for (int i=0;i<2*ND;++i) a[i] = 0.f;
  for (int q = beg; q < end; q += 6){
    int2 e[6]; float w[6];
#pragma unroll
    for (int j=0;j<6;++j){
      e[j] = cedge[min(q+j, ce)];
      w[j] = (q+j < end) ? __int_as_float(e[j].y) : 0.f;
    }
    unsigned int p[6][ND];
#pragma unroll
    for (int j=0;j<6;++j){
      const unsigned int* r = (const unsigned int*)(Xh + ((size_t)e[j].x*64 + l)*6);
#pragma unroll
      for (int i=0;i<ND;++i) p[j][i] = r[D0+i];
    }
#pragma unroll
    for (int j=0;j<6;++j)
#pragma unroll
      for (int i=0;i<ND;++i){
        a[2*i]   += w[j]*bf2f((unsigned short)(p[j][i] & 0xffffu));
        a[2*i+1] += w[j]*bf2f((unsigned short)(p[j][i] >> 16));
      }
  }
  unsigned int* uc = (unsigned int*)(Uh + ((size_t)n*64 + l)*6);
#pragma unroll
  for (int i=0;i<ND;++i){
    unsigned short u0 = f2bf(a[2*i]), u1 = f2bf(a[2*i+1]);
    int tp = 2*(D0+i);
    AxtH[((size_t)tp*N_PAD + n)*AXC + 64 + l]     = u0;
    AxtH[((size_t)(tp+1)*N_PAD + n)*AXC + 64 + l] = u1;
    uc[D0+i] = (unsigned int)u0 | ((unsigned int)u1 << 16);
  }
}
template<int D0, int ND>
__device__ __forceinline__ void xsp2_body(const unsigned short* __restrict__ Uh,
    unsigned short* __restrict__ AxtH,
    int n, int l, const int* __restrict__ offs, const int2* __restrict__ cedge)
{
  int beg = offs[n], end = offs[n+1];
  int ce = end - 1;
  float a[2*ND];
#pragma unroll
  for (int i=0;i<2*ND;++i) a[i] = 0.f;
  for (int q = beg; q < end; q += 6){
    int2 e[6]; float w[6];
#pragma unroll
    for (int j=0;j<6;++j){
      e[j] = cedge[min(q+j, ce)];
      w[j] = (q+j < end) ? __int_as_float(e[j].y) : 0.f;
    }
    unsigned int p[6][ND];
#pragma unroll
    for (int j=0;j<6;++j){
      const unsigned int* r = (const unsigned int*)(Uh + ((size_t)e[j].x*64 + l)*6);
#pragma unroll
      for (int i=0;i<ND;++i) p[j][i] = r[D0+i];
    }
#pragma unroll
    for (int j=0;j<6;++j)
#pragma unroll
      for (int i=0;i<ND;++i){
        a[2*i]   += w[j]*bf2f((unsigned short)(p[j][i] & 0xffffu));
        a[2*i+1] += w[j]*bf2f((unsigned short)(p[j][i] >> 16));
      }
  }
#pragma unroll
  for (int i=0;i<ND;++i){
    int tp = 2*(D0+i);
    AxtH[((size_t)tp*N_PAD + n)*AXC + 128 + l]     = f2bf(a[2*i]);
    AxtH[((size_t)(tp+1)*N_PAD + n)*AXC + 128 + l] = f2bf(a[2*i+1]);
  }
}

// prologue: t=0,1 planes only (dword0 of half 0)
__global__ void k_xsp1_t01(const unsigned short* __restrict__ Xtr, unsigned short* __restrict__ Axt,
                           unsigned short* __restrict__ U1tr,
                           const int* __restrict__ offs, const int2* __restrict__ cedge){
  int n = blockIdx.x*4 + (threadIdx.x >> 6);
  int l = threadIdx.x & 63;
  if (n >= N_NODE) return;
  xsp1_body<0,1>(Xtr, Axt, U1tr, n, l, offs, cedge);
}
__global__ void k_xsp2_t01(const unsigned short* __restrict__ U1tr, unsigned short* __restrict__ Axt,
                           const int* __restrict__ offs, const int2* __restrict__ cedge){
  int n = blockIdx.x*4 + (threadIdx.x >> 6);
  int l = threadIdx.x & 63;
  if (n >= N_NODE) return;
  xsp2_body<0,1>(U1tr, Axt, n, l, offs, cedge);
}

// ---------------- per-step h-side spmm bodies ----------------
__device__ __forceinline__ void spmm1_body(int n, int l,
    const unsigned short* __restrict__ Hc, unsigned short* __restrict__ U,
    const int* __restrict__ offs, const int2* __restrict__ cedge)
{
  if (n >= N_NODE) return;
  int sub = l >> 4, fl = l & 15;
  int beg = offs[n], end = offs[n+1];
  int ce = end - 1;
  float a[8];
#pragma unroll
  for (int j=0;j<8;++j) a[j] = 0.f;
  for (int q = beg; q < end; q += 16){
    int i0 = q + sub, i1 = q + 4 + sub, i2 = q + 8 + sub, i3 = q + 12 + sub;
    int2 e0 = cedge[min(i0, ce)];
    int2 e1 = cedge[min(i1, ce)];
    int2 e2 = cedge[min(i2, ce)];
    int2 e3 = cedge[min(i3, ce)];
    float w0 = (i0 < end) ? __int_as_float(e0.y) : 0.f;
    float w1 = (i1 < end) ? __int_as_float(e1.y) : 0.f;
    float w2 = (i2 < end) ? __int_as_float(e2.y) : 0.f;
    float w3 = (i3 < end) ? __int_as_float(e3.y) : 0.f;
    uint4 h0 = *(const uint4*)(Hc + (size_t)e0.x*128 + fl*8);
    uint4 h1 = *(const uint4*)(Hc + (size_t)e1.x*128 + fl*8);
    uint4 h2 = *(const uint4*)(Hc + (size_t)e2.x*128 + fl*8);
    uint4 h3 = *(const uint4*)(Hc + (size_t)e3.x*128 + fl*8);
    acc8(a, h0, w0);
    acc8(a, h1, w1);
    acc8(a, h2, w2);
    acc8(a, h3, w3);
  }
#pragma unroll
  for (int j=0;j<8;++j){
    a[j] += __shfl_xor(a[j], 16);
    a[j] += __shfl_xor(a[j], 32);
  }
  if (sub == 0){
    unsigned short o[8];
#pragma unroll
    for (int j=0;j<8;++j) o[j] = f2bf(a[j]);
    *(uint4*)(U + (size_t)n*256 + fl*8) = *(const uint4*)o;
  }
}
__device__ __forceinline__ void spmm2_body(int n, int l,
    unsigned short* __restrict__ U,
    const int* __restrict__ offs, const int2* __restrict__ cedge)
{
  if (n >= N_NODE) return;
  int sub = l >> 4, fl = l & 15;
  int beg = offs[n], end = offs[n+1];
  int ce = end - 1;
  float a[8];
#pragma unroll
  for (int j=0;j<8;++j) a[j] = 0.f;
  for (int q = beg; q < end; q += 16){
    int i0 = q + sub, i1 = q + 4 + sub, i2 = q + 8 + sub, i3 = q + 12 + sub;
    int2 e0 = cedge[min(i0, ce)];
    int2 e1 = cedge[min(i1, ce)];
    int2 e2 = cedge[min(i2, ce)];
    int2 e3 = cedge[min(i3, ce)];
    float w0 = (i0 < end) ? __int_as_float(e0.y) : 0.f;
    float w1 = (i1 < end) ? __int_as_float(e1.y) : 0.f;
    float w2 = (i2 < end) ? __int_as_float(e2.y) : 0.f;
    float w3 = (i3 < end) ? __int_as_float(e3.y) : 0.f;
    uint4 h0 = *(const uint4*)(U + (size_t)e0.x*256 + fl*8);
    uint4 h1 = *(const uint4*)(U + (size_t)e1.x*256 + fl*8);
    uint4 h2 = *(const uint4*)(U + (size_t)e2.x*256 + fl*8);
    uint4 h3 = *(const uint4*)(U + (size_t)e3.x*256 + fl*8);
    acc8(a, h0, w0);
    acc8(a, h1, w1);
    acc8(a, h2, w2);
    acc8(a, h3, w3);
  }
#pragma unroll
  for (int j=0;j<8;++j){
    a[j] += __shfl_xor(a[j], 16);
    a[j] += __shfl_xor(a[j], 32);
  }
  if (sub == 0){
    unsigned short o[8];
#pragma unroll
    for (int j=0;j<8;++j) o[j] = f2bf(a[j]);
    *(uint4*)(U + (size_t)n*256 + 128 + fl*8) = *(const uint4*)o;
  }
}

// ---------------- LN + MLP body (W1 read from L2, no LDS staging) ----------------
__device__ __forceinline__ void lnmlp_body(int n0,
    const unsigned short* __restrict__ Hn,
    const unsigned short* __restrict__ W1t, const float* __restrict__ b1p,
    const float* __restrict__ W2p, const float* __restrict__ b2,
    const float* __restrict__ gam, const float* __restrict__ bet,
    float* __restrict__ out, int t)
{
  __shared__ __align__(16) unsigned short xn[64*128];
  __shared__ float w2s[HID_P*2];
  __shared__ float b1s[HID_P];
  __shared__ float b2s[2];
  int tid = threadIdx.x;
  if (tid < HID_P*2) w2s[tid] = W2p[tid];
  if (tid < HID_P)   b1s[tid] = b1p[tid];
  if (tid < 2)       b2s[tid] = b2[tid];
  int row = tid >> 2, part = tid & 3;
  int n = n0 + row;
  float vals[32];
  float s = 0.f, ss = 0.f;
  if (n < N_NODE){
    const unsigned short* hp = Hn + (size_t)n*128 + part*32;
#pragma unroll
    for (int k=0;k<32;++k){
      float x = ftanh(bf2f(hp[k]));
      vals[k] = x; s += x; ss += x*x;
    }
  } else {
#pragma unroll
    for (int k=0;k<32;++k) vals[k] = 0.f;
  }
  s  += __shfl_xor(s,1);  s  += __shfl_xor(s,2);
  ss += __shfl_xor(ss,1); ss += __shfl_xor(ss,2);
  float mu = s * (1.f/128.f);
  float var = ss * (1.f/128.f) - mu*mu;
  float inv = rsqrtf(fmaxf(var, 0.f) + 1e-5f);
#pragma unroll
  for (int k=0;k<32;++k){
    int d = part*32 + k;
    xn[row*128 + d] = f2bf((vals[k]-mu)*inv*gam[d] + bet[d]);
  }
  __syncthreads();
  int w = tid >> 6, l = tid & 63;
  const f32x4 vzero = {0.f,0.f,0.f,0.f};
  f32x4 acc[5];
#pragma unroll
  for (int tj=0;tj<5;++tj) acc[tj] = vzero;
#pragma unroll
  for (int kk=0;kk<4;++kk){
    bf16x8 a = *(const bf16x8*)(xn + (w*16 + (l&15))*128 + kk*32 + (l>>4)*8);
#pragma unroll
    for (int tj=0;tj<5;++tj){
      bf16x8 b = *(const bf16x8*)(W1t + (tj*16 + (l&15))*128 + kk*32 + (l>>4)*8);
      acc[tj] = __builtin_amdgcn_mfma_f32_16x16x32_bf16(a, b, acc[tj], 0,0,0);
    }
  }
#pragma unroll
  for (int r=0;r<4;++r){
    int rn = n0 + w*16 + (l>>4)*4 + r;
    float p0 = 0.f, p1 = 0.f;
#pragma unroll
    for (int tj=0;tj<5;++tj){
      int col = tj*16 + (l&15);
      float hv = fmaxf(acc[tj][r] + b1s[col], 0.f);
      p0 += hv * w2s[col*2];
      p1 += hv * w2s[col*2+1];
    }
    p0 += __shfl_xor(p0,1); p0 += __shfl_xor(p0,2); p0 += __shfl_xor(p0,4); p0 += __shfl_xor(p0,8);
    p1 += __shfl_xor(p1,1); p1 += __shfl_xor(p1,2); p1 += __shfl_xor(p1,4); p1 += __shfl_xor(p1,8);
    if ((l & 15) == 0 && rn < N_NODE){
      float* op = out + (size_t)rn*24 + t;
      op[0]  = sigf(p0 + b2s[0]);
      op[12] = sigf(p1 + b2s[1]);
    }
  }
}

// ------- fusion: spmm1(t) + [xsp1 rest: xmode 1 = h0 d1-2, 2 = h1 d0-2] + lnmlp(t-1) -------
__global__ void k_sp1ln(const unsigned short* __restrict__ Hc, unsigned short* __restrict__ U,
                        const int* __restrict__ offs, const int2* __restrict__ cedge,
                        const unsigned short* __restrict__ W1t, const float* __restrict__ b1p,
                        const float* __restrict__ W2p, const float* __restrict__ b2,
                        const float* __restrict__ gam, const float* __restrict__ bet,
                        float* __restrict__ out, int tprev, int xmode, int nx,
                        const unsigned short* __restrict__ Xtr,
                        unsigned short* __restrict__ Axt, unsigned short* __restrict__ U1tr)
{
  int bb = blockIdx.x;
  int l = threadIdx.x & 63;
  if (bb < NB_SPMM){
    spmm1_body(bb*4 + (threadIdx.x >> 6), l, Hc, U, offs, cedge);
  } else if (bb < NB_SPMM + nx){
    int n = (bb - NB_SPMM)*4 + (threadIdx.x >> 6);
    if (n < N_NODE){
      if (xmode == 1)
        xsp1_body<1,2>(Xtr, Axt, U1tr, n, l, offs, cedge);
      else
        xsp1_body<0,3>(Xtr + (size_t)N_PAD*384, Axt + (size_t)6*N_PAD*AXC,
                       U1tr + (size_t)N_PAD*384, n, l, offs, cedge);
    }
  } else {
    lnmlp_body((bb - NB_SPMM - nx)*64, Hc, W1t, b1p, W2p, b2, gam, bet, out, tprev);
  }
}

// ------- fusion: spmm2(t) + [xsp2 rest] -------
__global__ void k_spmm2(unsigned short* __restrict__ U,
                        const int* __restrict__ offs, const int2* __restrict__ cedge,
                        int xmode, const unsigned short* __restrict__ U1tr,
                        unsigned short* __restrict__ Axt)
{
  int bb = blockIdx.x;
  int l = threadIdx.x & 63;
  if (bb < NB_SPMM){
    spmm2_body(bb*4 + (threadIdx.x >> 6), l, U, offs, cedge);
  } else {
    int n = (bb - NB_SPMM)*4 + (threadIdx.x >> 6);
    if (n < N_NODE){
      if (xmode == 1)
        xsp2_body<1,2>(U1tr, Axt, n, l, offs, cedge);
      else
        xsp2_body<0,3>(U1tr + (size_t)N_PAD*384, Axt + (size_t)6*N_PAD*AXC,
                       n, l, offs, cedge);
    }
  }
}

__global__ __launch_bounds__(256,2) void k_lnmlp(const unsigned short* __restrict__ Hn,
                        const unsigned short* __restrict__ W1t, const float* __restrict__ b1p,
                        const float* __restrict__ W2p, const float* __restrict__ b2,
                        const float* __restrict__ gam, const float* __restrict__ bet,
                        float* __restrict__ out, int t)
{
  lnmlp_body(blockIdx.x*64, Hn, W1t, b1p, W2p, b2, gam, bet, out, t);
}

// ---------------- fused GEMM + LSTM gates (bf16 c, epilogue loads) ----------
__global__ __launch_bounds__(256,3) void k_gemm(
    const unsigned short* __restrict__ Hc, const unsigned short* __restrict__ U,
    const unsigned short* __restrict__ Axt,
    const unsigned short* __restrict__ Bct, const float* __restrict__ btot,
    const float* __restrict__ wc, unsigned short* __restrict__ cst,
    unsigned short* __restrict__ Hn, int it0)
{
  int L = blockIdx.y*4 + blockIdx.x;
  int xcd = L & 7, li = L >> 3;
  int by = xcd + ((li >> 2) << 3);
  int bx = li & 3;
  if (by >= N_PAD/128) return;
  __shared__ __align__(16) unsigned short As[128*64];
  __shared__ __align__(16) unsigned short Bs[128*64];
  int tid = threadIdx.x;
  int w = tid >> 6, l = tid & 63;
  int n0 = bx * 128;
  int m0 = by * 128;
  const f32x4 vzero = {0.f,0.f,0.f,0.f};
  f32x4 acc[4][4];
#pragma unroll
  for (int i=0;i<4;++i)
#pragma unroll
    for (int j=0;j<4;++j) acc[i][j] = vzero;
  int wr = w >> 1, wn = w & 1;
  for (int it=it0; it<9; ++it){
    const unsigned short* Ab; int astr, acol;
    if (it < 2)      { Ab = Hc;  astr = 128; acol = it*64; }
    else if (it < 6) { Ab = U;   astr = 256; acol = (it-2)*64; }
    else             { Ab = Axt; astr = AXC; acol = (it-6)*64; }
    if (it != it0) __syncthreads();
#pragma unroll
    for (int i=0;i<4;++i){
      int rr = w*32 + i*8;
      int row = rr + (l>>3);
      gload16(Ab  + (size_t)(m0+row)*astr + acol + (l&7)*8, (void*)(As + rr*64));
      gload16(Bct + (size_t)(n0+row)*K_TOT + it*64 + (l&7)*8, (void*)(Bs + rr*64));
    }
    __syncthreads();
#pragma unroll
    for (int kk=0; kk<2; ++kk){
      bf16x8 af[4], bfv[4];
#pragma unroll
      for (int i=0;i<4;++i) af[i]  = *(const bf16x8*)(As + (wr*64 + i*16 + (l&15))*64 + kk*32 + (l>>4)*8);
#pragma unroll
      for (int j=0;j<4;++j) bfv[j] = *(const bf16x8*)(Bs + (wn*64 + j*16 + (l&15))*64 + kk*32 + (l>>4)*8);
#pragma unroll
      for (int i=0;i<4;++i)
#pragma unroll
        for (int j=0;j<4;++j)
          acc[i][j] = __builtin_amdgcn_mfma_f32_16x16x32_bf16(af[i], bfv[j], acc[i][j], 0,0,0);
    }
  }
  int dd = (((bx<<1) + wn) << 4) | (l & 15);
  float b_i = btot[dd], b_f = btot[128+dd], b_t = btot[256+dd], b_o = btot[384+dd];
  float wci = wc[dd], wcf = wc[128+dd], wco = wc[256+dd];
#pragma unroll
  for (int i=0;i<4;++i){
    int row0 = m0 + wr*64 + i*16 + (l>>4)*4;
#pragma unroll
    for (int r=0;r<4;++r){
      int row = row0 + r;
      float co = bf2f(cst[(size_t)row*128 + dd]);
      float gi = sigf(acc[i][0][r] + b_i + wci*co);
      float gf = sigf(acc[i][1][r] + b_f + wcf*co);
      float tt = ftanh(acc[i][2][r] + b_t);
      float cn = gf*co + gi*tt;
      float go = sigf(acc[i][3][r] + b_o + wco*cn);
      float h = go * ftanh(cn);
      cst[(size_t)row*128 + dd] = f2bf(cn);
      Hn[(size_t)row*128 + dd] = f2bf(h);
    }
  }
}

extern "C" void kernel_launch(void* const* d_in, const int* in_sizes, int n_in,
                              void* d_out, int out_size, void* d_ws, size_t ws_size,
                              hipStream_t stream)
{
  const float* H   = (const float*)d_in[0];
  const int*   ei  = (const int*)d_in[1];
  const float* Wx  = (const float*)d_in[2];
  const float* bx  = (const float*)d_in[3];
  const float* Wh  = (const float*)d_in[4];
  const float* bh  = (const float*)d_in[5];
  const float* bg  = (const float*)d_in[6];
  const float* wc  = (const float*)d_in[7];
  const float* gam = (const float*)d_in[8];
  const float* bet = (const float*)d_in[9];
  const float* W1  = (const float*)d_in[10];
  const float* b1  = (const float*)d_in[11];
  const float* W2  = (const float*)d_in[12];
  const float* b2  = (const float*)d_in[13];
  float* out = (float*)d_out;
  (void)in_sizes; (void)n_in; (void)out_size; (void)ws_size;

  char* p = (char*)d_ws;
  auto alloc = [&](size_t bytes)->char*{ char* r = p; p += (bytes + 255) & ~(size_t)255; return r; };
  // ---- zeroed region ----
  char* zbase = p;
  unsigned short* c_st = (unsigned short*)alloc((size_t)N_PAD*128*2);
  int* dsrc   = (int*)alloc((size_t)N_P2*4);
  int* ddst   = (int*)alloc((size_t)N_P2*4);
  int* cursor = (int*)alloc((size_t)N_P2*4);
  size_t zbytes = (size_t)(p - zbase);
  // ---- rest ----
  unsigned short* Hbuf0 = (unsigned short*)alloc((size_t)N_PAD*128*2);
  unsigned short* Hbuf1 = (unsigned short*)alloc((size_t)N_PAD*128*2);
  unsigned short* Ubuf  = (unsigned short*)alloc((size_t)N_PAD*256*2);
  unsigned short* Xtr   = (unsigned short*)alloc((size_t)N_PAD*768*2);
  unsigned short* U1tr  = (unsigned short*)alloc((size_t)N_PAD*768*2);
  unsigned short* Axt   = (unsigned short*)alloc((size_t)S_DIM*N_PAD*AXC*2);
  unsigned short* Bct   = (unsigned short*)alloc((size_t)N_COL*K_TOT*2);
  float*          btot  = (float*)alloc(N_COL*4);
  unsigned short* W1t   = (unsigned short*)alloc(HID_P*128*2);
  float*          b1p   = (float*)alloc(HID_P*4);
  float*          W2p   = (float*)alloc(HID_P*2*4);
  float*          dinv  = (float*)alloc((size_t)N_P2*4);
  int*            offs  = (int*)alloc((size_t)(N_P2+256)*4);
  int*            outp  = (int*)alloc((size_t)N_P2*4);
  int*            partb = (int*)alloc(256*4);
  int2*           cedge = (int2*)alloc((size_t)N_E*8);

  hipMemsetAsync(zbase, 0, zbytes, stream);
  k_setup<<<NB_PREP + NB_DEG, 256, 0, stream>>>(ei, Wx, Wh, bx, bh, bg,
      W1, b1, W2, Bct, btot, W1t, b1p, W2p, dsrc, ddst);
  k_xprep<<<N_PAD/32, 256, 0, stream>>>(H, Xtr, Axt);
  k_scan1d<<<N_P2/256, 256, 0, stream>>>(ddst, outp, partb, dsrc, dinv);
  k_scan3f<<<N_P2/256, 256, 0, stream>>>(outp, partb, offs);
  k_csr<<<NB_DEG, 256, 0, stream>>>(ei, dinv, offs, cursor, cedge);
  // prologue computes only x-planes t=0,1; planes 2-5 ride in t=1 dispatches,
  // planes 6-11 in t=2 dispatches (deadline: gemm(2)/gemm(6)).
  k_xsp1_t01<<<NB_SPMM, 256, 0, stream>>>(Xtr, Axt, U1tr, offs, cedge);
  k_xsp2_t01<<<NB_SPMM, 256, 0, stream>>>(U1tr, Axt, offs, cedge);

  // t = 0: h == 0 -> only x-part of K (it0 = 6); Hc/U never read.
  k_gemm<<<dim3(4, 392), 256, 0, stream>>>(Hbuf0, Ubuf, Axt,
      Bct, btot, wc, c_st, Hbuf1, 6);
  for (int t = 1; t < S_DIM; ++t){
    unsigned short* Hc = (t & 1) ? Hbuf1 : Hbuf0;
    unsigned short* Hn = (t & 1) ? Hbuf0 : Hbuf1;
    int xmode = (t == 1) ? 1 : (t == 2) ? 2 : 0;
    int nx = xmode ? NB_SPMM : 0;
    k_sp1ln<<<NB_SPMM + nx + NB_LN, 256, 0, stream>>>(Hc, Ubuf, offs, cedge,
        W1t, b1p, W2p, b2, gam, bet, out, t-1, xmode, nx, Xtr, Axt, U1tr);
    k_spmm2<<<NB_SPMM + nx, 256, 0, stream>>>(Ubuf, offs, cedge, xmode, U1tr, Axt);
    k_gemm<<<dim3(4, 392), 256, 0, stream>>>(Hc, Ubuf,
        Axt + (size_t)t*N_PAD*AXC, Bct, btot, wc, c_st, Hn, 0);
  }
  k_lnmlp<<<NB_LN, 256, 0, stream>>>(Hbuf0, W1t, b1p, W2p, b2, gam, bet, out, 11);
}

// Round 12
// 1854.543 us; speedup vs baseline: 1.0894x; 1.0894x over previous
//
#include <hip/hip_runtime.h>
#include <cstdint>
#include <cstddef>

#define S_DIM 12
#define N_NODE 50000
#define N_PAD 50048
#define N_P2 50176
#define D_IN 64
#define D_H 128
#define N_E 600000
#define K_TOT 576
#define N_COL 512
#define HID_P 80
#define N_HID 65
#define AXC 192

#define NB_PREP 1152
#define NB_XPREP 12512
#define NB_DEG 2344
#define NB_SPMM 12500
#define NB_LN 782

typedef short bf16x8 __attribute__((ext_vector_type(8)));
typedef float f32x4 __attribute__((ext_vector_type(4)));

__device__ __forceinline__ float bf2f(unsigned short u){
  union { unsigned int i; float f; } v; v.i = ((unsigned int)u) << 16; return v.f;
}
__device__ __forceinline__ unsigned short f2bf(float f){
  union { float f; unsigned int i; } v; v.f = f;
  unsigned int x = v.i;
  return (unsigned short)((x + 0x7fffu + ((x >> 16) & 1u)) >> 16);
}
__device__ __forceinline__ float sigf(float x){ return 1.f/(1.f + __expf(-x)); }
__device__ __forceinline__ float ftanh(float x){
  x = fminf(fmaxf(x, -12.f), 12.f);
  float e = __expf(2.f*x);
  return (e - 1.f)/(e + 1.f);
}
__device__ __forceinline__ void gload16(const void* g, void* lds){
  __builtin_amdgcn_global_load_lds((const __attribute__((address_space(1))) unsigned int*)g,
                                   (__attribute__((address_space(3))) unsigned int*)lds, 16, 0, 0);
}
// accumulate 6 bf16 (3 dwords) * w
__device__ __forceinline__ void acc6(float* a, unsigned int p0, unsigned int p1, unsigned int p2, float w){
  unsigned int u[3] = {p0, p1, p2};
#pragma unroll
  for (int i=0;i<3;++i){
    a[2*i]   += w * bf2f((unsigned short)(u[i] & 0xffffu));
    a[2*i+1] += w * bf2f((unsigned short)(u[i] >> 16));
  }
}
// accumulate 8 bf16 (uint4) * w
__device__ __forceinline__ void acc8(float* a, uint4 h, float w){
  unsigned int u[4] = {h.x, h.y, h.z, h.w};
#pragma unroll
  for (int i=0;i<4;++i){
    a[2*i]   += w * bf2f((unsigned short)(u[i] & 0xffffu));
    a[2*i+1] += w * bf2f((unsigned short)(u[i] >> 16));
  }
}

// ---------------- fused setup: weight pack + x convert + degree count ----------
__global__ void k_setup(const float* __restrict__ H, const int* __restrict__ ei,
                        const float* __restrict__ Wx, const float* __restrict__ Wh,
                        const float* __restrict__ bx, const float* __restrict__ bh,
                        const float* __restrict__ bg, const float* __restrict__ W1,
                        const float* __restrict__ b1, const float* __restrict__ W2,
                        unsigned short* __restrict__ Bct, float* __restrict__ btot,
                        unsigned short* __restrict__ W1t, float* __restrict__ b1p,
                        float* __restrict__ W2p, unsigned short* __restrict__ Xtr,
                        unsigned short* __restrict__ Axt,
                        int* __restrict__ dsrc, int* __restrict__ ddst)
{
  int bb = blockIdx.x, tid = threadIdx.x;
  if (bb < NB_PREP){
    int idx = bb*256 + tid;
    if (idx < N_COL*K_TOT){
      int cc = idx / K_TOT, k = idx - cc*K_TOT;
      int g = (cc>>4)&3, d = (cc&15) + ((cc>>6)<<4);
      float v;
      if (k < 384){
        int kt = k >> 7, j = k & 127;
        const float* Wg = Wh + (size_t)g*3*128*128;
        if (kt == 0)      v = Wg[(size_t)j*128 + d] - Wg[(size_t)(256+j)*128 + d];
        else if (kt == 1) v = Wg[(size_t)(128+j)*128 + d];
        else              v = 2.f*Wg[(size_t)(256+j)*128 + d];
      } else {
        int kk = k - 384; int kt = kk >> 6, j = kk & 63;
        const float* Wg = Wx + (size_t)g*3*64*128;
        if (kt == 0)      v = Wg[(size_t)j*128 + d] - Wg[(size_t)(128+j)*128 + d];
        else if (kt == 1) v = Wg[(size_t)(64+j)*128 + d];
        else              v = 2.f*Wg[(size_t)(128+j)*128 + d];
      }
      Bct[(size_t)cc*K_TOT + k] = f2bf(v);
    }
    if (idx < N_COL) btot[idx] = bx[idx] + bh[idx] + bg[idx];
    if (idx < HID_P*D_H){ int c = idx >> 7, k = idx & 127;
      W1t[idx] = (c < N_HID) ? f2bf(W1[k*N_HID + c]) : (unsigned short)0; }
    if (idx < HID_P) b1p[idx] = (idx < N_HID) ? b1[idx] : 0.f;
    if (idx < HID_P*2){ int c = idx >> 1, j = idx & 1; W2p[idx] = (c < N_HID) ? W2[c*2 + j] : 0.f; }
  } else if (bb < NB_PREP + NB_XPREP){
    int idx = (bb - NB_PREP)*256 + tid;      // (n,d)
    int n = idx >> 6, d = idx & 63;
    unsigned short u[12];
    if (n < N_NODE){
#pragma unroll
      for (int t=0;t<12;++t) u[t] = f2bf(H[((size_t)t*N_NODE + n)*64 + d]);
    } else {
#pragma unroll
      for (int t=0;t<12;++t) u[t] = 0;
    }
    // Xtr halves: [h][n*64+d][6] dense
    unsigned int* x0 = (unsigned int*)(Xtr + (size_t)idx*6);
    unsigned int* x1 = (unsigned int*)(Xtr + (size_t)N_PAD*384 + (size_t)idx*6);
#pragma unroll
    for (int i=0;i<3;++i){
      x0[i] = (unsigned int)u[2*i]   | ((unsigned int)u[2*i+1] << 16);
      x1[i] = (unsigned int)u[6+2*i] | ((unsigned int)u[6+2*i+1] << 16);
    }
#pragma unroll
    for (int t=0;t<12;++t) Axt[((size_t)t*N_PAD + n)*AXC + d] = u[t];
    if (n >= N_NODE){
#pragma unroll
      for (int t=0;t<12;++t){
        Axt[((size_t)t*N_PAD + n)*AXC + 64 + d]  = 0;
        Axt[((size_t)t*N_PAD + n)*AXC + 128 + d] = 0;
      }
    }
  } else {
    int e = (bb - NB_PREP - NB_XPREP)*256 + tid;
    if (e < N_E){
      atomicAdd(&dsrc[ei[e]], 1);
      atomicAdd(&ddst[ei[N_E + e]], 1);
    }
  }
}

// ---------------- scans + csr ----------------
__global__ void k_scan1d(const int* __restrict__ in, int* __restrict__ outp, int* __restrict__ part,
                         const int* __restrict__ dsrc, float* __restrict__ dinv){
  __shared__ int sm[256];
  int tid = threadIdx.x;
  int i = blockIdx.x*256 + tid;
  dinv[i] = (dsrc[i] > 0) ? rsqrtf((float)dsrc[i]) : 0.f;
  int v = in[i];
  int x = v;
  sm[tid] = x; __syncthreads();
  for (int off=1; off<256; off<<=1){
    int y = (tid >= off) ? sm[tid-off] : 0;
    __syncthreads();
    x += y; sm[tid] = x; __syncthreads();
  }
  outp[i] = x - v;
  if (tid == 255) part[blockIdx.x] = x;
}
// fused: every block re-scans the 196 partials, takes its exclusive prefix
__global__ void k_scan3f(const int* __restrict__ outp, const int* __restrict__ part,
                         int* __restrict__ offs){
  __shared__ int sm[256];
  int tid = threadIdx.x;
  int v = (tid < N_P2/256) ? part[tid] : 0;
  int x = v; sm[tid] = x; __syncthreads();
  for (int off=1; off<256; off<<=1){
    int y = (tid >= off) ? sm[tid-off] : 0;
    __syncthreads();
    x += y; sm[tid] = x; __syncthreads();
  }
  int pref = (blockIdx.x > 0) ? sm[blockIdx.x - 1] : 0;
  int i = blockIdx.x*256 + tid;
  offs[i] = outp[i] + pref;
}
__global__ void k_csr(const int* __restrict__ ei, const float* __restrict__ dinv,
                      const int* __restrict__ offs, int* __restrict__ cursor,
                      int2* __restrict__ cedge){
  int e = blockIdx.x*256 + threadIdx.x;
  if (e < N_E){
    int s = ei[e], d = ei[N_E + e];
    int pos = atomicAdd(&cursor[d], 1);
    float w = -dinv[s]*dinv[d];
    cedge[offs[d] + pos] = make_int2(s, __float_as_int(w));
  }
}

// ---------------- x-side spmm, both t-halves in one dispatch ----------
__global__ void k_xspmm1(const unsigned short* __restrict__ Xtr, unsigned short* __restrict__ Axt,
                         unsigned short* __restrict__ U1tr,
                         const int* __restrict__ offs, const int2* __restrict__ cedge){
  int bb = blockIdx.x;
  int h = (bb >= NB_SPMM) ? 1 : 0;
  const unsigned short* Xh = Xtr + (size_t)h*N_PAD*384;
  unsigned short* AxtH = Axt + (size_t)h*6*N_PAD*AXC;
  unsigned short* Uh = U1tr + (size_t)h*N_PAD*384;
  int n = (bb - h*NB_SPMM)*4 + (threadIdx.x >> 6);
  int l = threadIdx.x & 63;
  if (n >= N_NODE) return;
  int beg = offs[n], end = offs[n+1];
  int ce = end - 1;
  float a[6];
#pragma unroll
  for (int t=0;t<6;++t) a[t] = 0.f;
  for (int q = beg; q < end; q += 6){
    int2 e0 = cedge[min(q,   ce)];
    int2 e1 = cedge[min(q+1, ce)];
    int2 e2 = cedge[min(q+2, ce)];
    int2 e3 = cedge[min(q+3, ce)];
    int2 e4 = cedge[min(q+4, ce)];
    int2 e5 = cedge[min(q+5, ce)];
    float w0 = __int_as_float(e0.y);
    float w1 = (q+1 < end) ? __int_as_float(e1.y) : 0.f;
    float w2 = (q+2 < end) ? __int_as_float(e2.y) : 0.f;
    float w3 = (q+3 < end) ? __int_as_float(e3.y) : 0.f;
    float w4 = (q+4 < end) ? __int_as_float(e4.y) : 0.f;
    float w5 = (q+5 < end) ? __int_as_float(e5.y) : 0.f;
    const unsigned int* r0 = (const unsigned int*)(Xh + ((size_t)e0.x*64 + l)*6);
    const unsigned int* r1 = (const unsigned int*)(Xh + ((size_t)e1.x*64 + l)*6);
    const unsigned int* r2 = (const unsigned int*)(Xh + ((size_t)e2.x*64 + l)*6);
    const unsigned int* r3 = (const unsigned int*)(Xh + ((size_t)e3.x*64 + l)*6);
    const unsigned int* r4 = (const unsigned int*)(Xh + ((size_t)e4.x*64 + l)*6);
    const unsigned int* r5 = (const unsigned int*)(Xh + ((size_t)e5.x*64 + l)*6);
    unsigned int p00=r0[0], p01=r0[1], p02=r0[2];
    unsigned int p10=r1[0], p11=r1[1], p12=r1[2];
    unsigned int p20=r2[0], p21=r2[1], p22=r2[2];
    unsigned int p30=r3[0], p31=r3[1], p32=r3[2];
    unsigned int p40=r4[0], p41=r4[1], p42=r4[2];
    unsigned int p50=r5[0], p51=r5[1], p52=r5[2];
    acc6(a, p00, p01, p02, w0);
    acc6(a, p10, p11, p12, w1);
    acc6(a, p20, p21, p22, w2);
    acc6(a, p30, p31, p32, w3);
    acc6(a, p40, p41, p42, w4);
    acc6(a, p50, p51, p52, w5);
  }
  unsigned short u[6];
#pragma unroll
  for (int t=0;t<6;++t){
    u[t] = f2bf(a[t]);
    AxtH[((size_t)t*N_PAD + n)*AXC + 64 + l] = u[t];
  }
  unsigned int* op = (unsigned int*)(Uh + ((size_t)n*64 + l)*6);
#pragma unroll
  for (int i=0;i<3;++i) op[i] = (unsigned int)u[2*i] | ((unsigned int)u[2*i+1] << 16);
}
__global__ void k_xspmm2(const unsigned short* __restrict__ U1tr, unsigned short* __restrict__ Axt,
                         const int* __restrict__ offs, const int2* __restrict__ cedge){
  int bb = blockIdx.x;
  int h = (bb >= NB_SPMM) ? 1 : 0;
  const unsigned short* Uh = U1tr + (size_t)h*N_PAD*384;
  unsigned short* AxtH = Axt + (size_t)h*6*N_PAD*AXC;
  int n = (bb - h*NB_SPMM)*4 + (threadIdx.x >> 6);
  int l = threadIdx.x & 63;
  if (n >= N_NODE) return;
  int beg = offs[n], end = offs[n+1];
  int ce = end - 1;
  float a[6];
#pragma unroll
  for (int t=0;t<6;++t) a[t] = 0.f;
  for (int q = beg; q < end; q += 6){
    int2 e0 = cedge[min(q,   ce)];
    int2 e1 = cedge[min(q+1, ce)];
    int2 e2 = cedge[min(q+2, ce)];
    int2 e3 = cedge[min(q+3, ce)];
    int2 e4 = cedge[min(q+4, ce)];
    int2 e5 = cedge[min(q+5, ce)];
    float w0 = __int_as_float(e0.y);
    float w1 = (q+1 < end) ? __int_as_float(e1.y) : 0.f;
    float w2 = (q+2 < end) ? __int_as_float(e2.y) : 0.f;
    float w3 = (q+3 < end) ? __int_as_float(e3.y) : 0.f;
    float w4 = (q+4 < end) ? __int_as_float(e4.y) : 0.f;
    float w5 = (q+5 < end) ? __int_as_float(e5.y) : 0.f;
    const unsigned int* r0 = (const unsigned int*)(Uh + ((size_t)e0.x*64 + l)*6);
    const unsigned int* r1 = (const unsigned int*)(Uh + ((size_t)e1.x*64 + l)*6);
    const unsigned int* r2 = (const unsigned int*)(Uh + ((size_t)e2.x*64 + l)*6);
    const unsigned int* r3 = (const unsigned int*)(Uh + ((size_t)e3.x*64 + l)*6);
    const unsigned int* r4 = (const unsigned int*)(Uh + ((size_t)e4.x*64 + l)*6);
    const unsigned int* r5 = (const unsigned int*)(Uh + ((size_t)e5.x*64 + l)*6);
    unsigned int p00=r0[0], p01=r0[1], p02=r0[2];
    unsigned int p10=r1[0], p11=r1[1], p12=r1[2];
    unsigned int p20=r2[0], p21=r2[1], p22=r2[2];
    unsigned int p30=r3[0], p31=r3[1], p32=r3[2];
    unsigned int p40=r4[0], p41=r4[1], p42=r4[2];
    unsigned int p50=r5[0], p51=r5[1], p52=r5[2];
    acc6(a, p00, p01, p02, w0);
    acc6(a, p10, p11, p12, w1);
    acc6(a, p20, p21, p22, w2);
    acc6(a, p30, p31, p32, w3);
    acc6(a, p40, p41, p42, w4);
    acc6(a, p50, p51, p52, w5);
  }
#pragma unroll
  for (int t=0;t<6;++t)
    AxtH[((size_t)t*N_PAD + n)*AXC + 128 + l] = f2bf(a[t]);
}

// ---------------- per-step h-side spmm bodies ----------------
__device__ __forceinline__ void spmm1_body(int n, int l,
    const unsigned short* __restrict__ Hc, unsigned short* __restrict__ U,
    const int* __restrict__ offs, const int2* __restrict__ cedge)
{
  if (n >= N_NODE) return;
  int sub = l >> 4, fl = l & 15;
  int beg = offs[n], end = offs[n+1];
  int ce = end - 1;
  float a[8];
#pragma unroll
  for (int j=0;j<8;++j) a[j] = 0.f;
  for (int q = beg; q < end; q += 16){
    int i0 = q + sub, i1 = q + 4 + sub, i2 = q + 8 + sub, i3 = q + 12 + sub;
    int2 e0 = cedge[min(i0, ce)];
    int2 e1 = cedge[min(i1, ce)];
    int2 e2 = cedge[min(i2, ce)];
    int2 e3 = cedge[min(i3, ce)];
    float w0 = (i0 < end) ? __int_as_float(e0.y) : 0.f;
    float w1 = (i1 < end) ? __int_as_float(e1.y) : 0.f;
    float w2 = (i2 < end) ? __int_as_float(e2.y) : 0.f;
    float w3 = (i3 < end) ? __int_as_float(e3.y) : 0.f;
    uint4 h0 = *(const uint4*)(Hc + (size_t)e0.x*128 + fl*8);
    uint4 h1 = *(const uint4*)(Hc + (size_t)e1.x*128 + fl*8);
    uint4 h2 = *(const uint4*)(Hc + (size_t)e2.x*128 + fl*8);
    uint4 h3 = *(const uint4*)(Hc + (size_t)e3.x*128 + fl*8);
    acc8(a, h0, w0);
    acc8(a, h1, w1);
    acc8(a, h2, w2);
    acc8(a, h3, w3);
  }
#pragma unroll
  for (int j=0;j<8;++j){
    a[j] += __shfl_xor(a[j], 16);
    a[j] += __shfl_xor(a[j], 32);
  }
  if (sub == 0){
    unsigned short o[8];
#pragma unroll
    for (int j=0;j<8;++j) o[j] = f2bf(a[j]);
    *(uint4*)(U + (size_t)n*256 + fl*8) = *(const uint4*)o;
  }
}

__global__ void k_spmm2(unsigned short* __restrict__ U,
                        const int* __restrict__ offs, const int2* __restrict__ cedge){
  int n = blockIdx.x*4 + (threadIdx.x >> 6);
  int l = threadIdx.x & 63;
  if (n >= N_NODE) return;
  int sub = l >> 4, fl = l & 15;
  int beg = offs[n], end = offs[n+1];
  int ce = end - 1;
  float a[8];
#pragma unroll
  for (int j=0;j<8;++j) a[j] = 0.f;
  for (int q = beg; q < end; q += 16){
    int i0 = q + sub, i1 = q + 4 + sub, i2 = q + 8 + sub, i3 = q + 12 + sub;
    int2 e0 = cedge[min(i0, ce)];
    int2 e1 = cedge[min(i1, ce)];
    int2 e2 = cedge[min(i2, ce)];
    int2 e3 = cedge[min(i3, ce)];
    float w0 = (i0 < end) ? __int_as_float(e0.y) : 0.f;
    float w1 = (i1 < end) ? __int_as_float(e1.y) : 0.f;
    float w2 = (i2 < end) ? __int_as_float(e2.y) : 0.f;
    float w3 = (i3 < end) ? __int_as_float(e3.y) : 0.f;
    uint4 h0 = *(const uint4*)(U + (size_t)e0.x*256 + fl*8);
    uint4 h1 = *(const uint4*)(U + (size_t)e1.x*256 + fl*8);
    uint4 h2 = *(const uint4*)(U + (size_t)e2.x*256 + fl*8);
    uint4 h3 = *(const uint4*)(U + (size_t)e3.x*256 + fl*8);
    acc8(a, h0, w0);
    acc8(a, h1, w1);
    acc8(a, h2, w2);
    acc8(a, h3, w3);
  }
#pragma unroll
  for (int j=0;j<8;++j){
    a[j] += __shfl_xor(a[j], 16);
    a[j] += __shfl_xor(a[j], 32);
  }
  if (sub == 0){
    unsigned short o[8];
#pragma unroll
    for (int j=0;j<8;++j) o[j] = f2bf(a[j]);
    *(uint4*)(U + (size_t)n*256 + 128 + fl*8) = *(const uint4*)o;
  }
}

// ---------------- LN + MLP body ----------------
__device__ __forceinline__ void lnmlp_body(int n0,
    const unsigned short* __restrict__ Hn,
    const unsigned short* __restrict__ W1t, const float* __restrict__ b1p,
    const float* __restrict__ W2p, const float* __restrict__ b2,
    const float* __restrict__ gam, const float* __restrict__ bet,
    float* __restrict__ out, int t)
{
  __shared__ __align__(16) unsigned short xn[64*128];
  __shared__ __align__(16) unsigned short w1s[HID_P*128];
  __shared__ float w2s[HID_P*2];
  __shared__ float b1s[HID_P];
  __shared__ float b2s[2];
  int tid = threadIdx.x;
  for (int i = tid; i < HID_P*128/8; i += 256) ((int4*)w1s)[i] = ((const int4*)W1t)[i];
  if (tid < HID_P*2) w2s[tid] = W2p[tid];
  if (tid < HID_P)   b1s[tid] = b1p[tid];
  if (tid < 2)       b2s[tid] = b2[tid];
  int row = tid >> 2, part = tid & 3;
  int n = n0 + row;
  float vals[32];
  float s = 0.f, ss = 0.f;
  if (n < N_NODE){
    const unsigned short* hp = Hn + (size_t)n*128 + part*32;
#pragma unroll
    for (int k=0;k<32;++k){
      float x = ftanh(bf2f(hp[k]));
      vals[k] = x; s += x; ss += x*x;
    }
  } else {
#pragma unroll
    for (int k=0;k<32;++k) vals[k] = 0.f;
  }
  s  += __shfl_xor(s,1);  s  += __shfl_xor(s,2);
  ss += __shfl_xor(ss,1); ss += __shfl_xor(ss,2);
  float mu = s * (1.f/128.f);
  float var = ss * (1.f/128.f) - mu*mu;
  float inv = rsqrtf(fmaxf(var, 0.f) + 1e-5f);
#pragma unroll
  for (int k=0;k<32;++k){
    int d = part*32 + k;
    xn[row*128 + d] = f2bf((vals[k]-mu)*inv*gam[d] + bet[d]);
  }
  __syncthreads();
  int w = tid >> 6, l = tid & 63;
  const f32x4 vzero = {0.f,0.f,0.f,0.f};
  f32x4 acc[5];
#pragma unroll
  for (int tj=0;tj<5;++tj) acc[tj] = vzero;
#pragma unroll
  for (int kk=0;kk<4;++kk){
    bf16x8 a = *(const bf16x8*)(xn + (w*16 + (l&15))*128 + kk*32 + (l>>4)*8);
#pragma unroll
    for (int tj=0;tj<5;++tj){
      bf16x8 b = *(const bf16x8*)(w1s + (tj*16 + (l&15))*128 + kk*32 + (l>>4)*8);
      acc[tj] = __builtin_amdgcn_mfma_f32_16x16x32_bf16(a, b, acc[tj], 0,0,0);
    }
  }
#pragma unroll
  for (int r=0;r<4;++r){
    int rn = n0 + w*16 + (l>>4)*4 + r;
    float p0 = 0.f, p1 = 0.f;
#pragma unroll
    for (int tj=0;tj<5;++tj){
      int col = tj*16 + (l&15);
      float hv = fmaxf(acc[tj][r] + b1s[col], 0.f);
      p0 += hv * w2s[col*2];
      p1 += hv * w2s[col*2+1];
    }
    p0 += __shfl_xor(p0,1); p0 += __shfl_xor(p0,2); p0 += __shfl_xor(p0,4); p0 += __shfl_xor(p0,8);
    p1 += __shfl_xor(p1,1); p1 += __shfl_xor(p1,2); p1 += __shfl_xor(p1,4); p1 += __shfl_xor(p1,8);
    if ((l & 15) == 0 && rn < N_NODE){
      float* op = out + (size_t)rn*24 + t;
      op[0]  = sigf(p0 + b2s[0]);
      op[12] = sigf(p1 + b2s[1]);
    }
  }
}

// ---------------- horizontal fusion: spmm1(t) || lnmlp(t-1) ----------------
__global__ void k_sp1ln(const unsigned short* __restrict__ Hc, unsigned short* __restrict__ U,
                        const int* __restrict__ offs, const int2* __restrict__ cedge,
                        const unsigned short* __restrict__ W1t, const float* __restrict__ b1p,
                        const float* __restrict__ W2p, const float* __restrict__ b2,
                        const float* __restrict__ gam, const float* __restrict__ bet,
                        float* __restrict__ out, int tprev)
{
  int bb = blockIdx.x;
  if (bb < NB_SPMM){
    spmm1_body(bb*4 + (threadIdx.x >> 6), threadIdx.x & 63, Hc, U, offs, cedge);
  } else {
    lnmlp_body((bb - NB_SPMM)*64, Hc, W1t, b1p, W2p, b2, gam, bet, out, tprev);
  }
}

__global__ __launch_bounds__(256,2) void k_lnmlp(const unsigned short* __restrict__ Hn,
                        const unsigned short* __restrict__ W1t, const float* __restrict__ b1p,
                        const float* __restrict__ W2p, const float* __restrict__ b2,
                        const float* __restrict__ gam, const float* __restrict__ bet,
                        float* __restrict__ out, int t)
{
  lnmlp_body(blockIdx.x*64, Hn, W1t, b1p, W2p, b2, gam, bet, out, t);
}

// ---------------- fused GEMM + LSTM gates (single-buf, 3 blocks/CU) ----------
__global__ __launch_bounds__(256,3) void k_gemm(
    const unsigned short* __restrict__ Hc, const unsigned short* __restrict__ U,
    const unsigned short* __restrict__ Axt,
    const unsigned short* __restrict__ Bct, const float* __restrict__ btot,
    const float* __restrict__ wc, float* __restrict__ c, unsigned short* __restrict__ Hn,
    int it0)
{
  __shared__ __align__(16) unsigned short As[128*64];
  __shared__ __align__(16) unsigned short Bs[128*64];
  int tid = threadIdx.x;
  int w = tid >> 6, l = tid & 63;
  const int NWG = 1564, q8 = NWG >> 3, r8 = NWG & 7;
  int L = blockIdx.y*4 + blockIdx.x;
  int xcd = L & 7, li = L >> 3;
  int W = (xcd < r8 ? xcd*(q8+1) : r8*(q8+1) + (xcd-r8)*q8) + li;
  int bx = W & 3, by = W >> 2;
  int n0 = bx * 128;
  int m0 = by * 128;
  const f32x4 vzero = {0.f,0.f,0.f,0.f};
  f32x4 acc[4][4];
#pragma unroll
  for (int i=0;i<4;++i)
#pragma unroll
    for (int j=0;j<4;++j) acc[i][j] = vzero;
  int wr = w >> 1, wn = w & 1;
  for (int it=it0; it<9; ++it){
    const unsigned short* Ab; int astr, acol;
    if (it < 2)      { Ab = Hc;  astr = 128; acol = it*64; }
    else if (it < 6) { Ab = U;   astr = 256; acol = (it-2)*64; }
    else             { Ab = Axt; astr = AXC; acol = (it-6)*64; }
    if (it != it0) __syncthreads();
#pragma unroll
    for (int i=0;i<4;++i){
      int rr = w*32 + i*8;
      int row = rr + (l>>3);
      gload16(Ab  + (size_t)(m0+row)*astr + acol + (l&7)*8, (void*)(As + rr*64));
      gload16(Bct + (size_t)(n0+row)*K_TOT + it*64 + (l&7)*8, (void*)(Bs + rr*64));
    }
    __syncthreads();
#pragma unroll
    for (int kk=0; kk<2; ++kk){
      bf16x8 af[4], bfv[4];
#pragma unroll
      for (int i=0;i<4;++i) af[i]  = *(const bf16x8*)(As + (wr*64 + i*16 + (l&15))*64 + kk*32 + (l>>4)*8);
#pragma unroll
      for (int j=0;j<4;++j) bfv[j] = *(const bf16x8*)(Bs + (wn*64 + j*16 + (l&15))*64 + kk*32 + (l>>4)*8);
#pragma unroll
      for (int i=0;i<4;++i)
#pragma unroll
        for (int j=0;j<4;++j)
          acc[i][j] = __builtin_amdgcn_mfma_f32_16x16x32_bf16(af[i], bfv[j], acc[i][j], 0,0,0);
    }
  }
  int dd = (((bx<<1) + wn) << 4) | (l & 15);
  float b_i = btot[dd], b_f = btot[128+dd], b_t = btot[256+dd], b_o = btot[384+dd];
  float wci = wc[dd], wcf = wc[128+dd], wco = wc[256+dd];
#pragma unroll
  for (int i=0;i<4;++i){
    int row0 = m0 + wr*64 + i*16 + (l>>4)*4;
#pragma unroll
    for (int r=0;r<4;++r){
      int row = row0 + r;
      float co = c[(size_t)row*128 + dd];
      float gi = sigf(acc[i][0][r] + b_i + wci*co);
      float gf = sigf(acc[i][1][r] + b_f + wcf*co);
      float tt = ftanh(acc[i][2][r] + b_t);
      float cn = gf*co + gi*tt;
      float go = sigf(acc[i][3][r] + b_o + wco*cn);
      float h = go * ftanh(cn);
      c[(size_t)row*128 + dd] = cn;
      Hn[(size_t)row*128 + dd] = f2bf(h);
    }
  }
}

extern "C" void kernel_launch(void* const* d_in, const int* in_sizes, int n_in,
                              void* d_out, int out_size, void* d_ws, size_t ws_size,
                              hipStream_t stream)
{
  const float* H   = (const float*)d_in[0];
  const int*   ei  = (const int*)d_in[1];
  const float* Wx  = (const float*)d_in[2];
  const float* bx  = (const float*)d_in[3];
  const float* Wh  = (const float*)d_in[4];
  const float* bh  = (const float*)d_in[5];
  const float* bg  = (const float*)d_in[6];
  const float* wc  = (const float*)d_in[7];
  const float* gam = (const float*)d_in[8];
  const float* bet = (const float*)d_in[9];
  const float* W1  = (const float*)d_in[10];
  const float* b1  = (const float*)d_in[11];
  const float* W2  = (const float*)d_in[12];
  const float* b2  = (const float*)d_in[13];
  float* out = (float*)d_out;
  (void)in_sizes; (void)n_in; (void)out_size; (void)ws_size;

  char* p = (char*)d_ws;
  auto alloc = [&](size_t bytes)->char*{ char* r = p; p += (bytes + 255) & ~(size_t)255; return r; };
  // ---- zeroed region ----
  char* zbase = p;
  float* c_st  = (float*)alloc((size_t)N_PAD*128*4);
  unsigned short* Ubuf = (unsigned short*)alloc((size_t)N_PAD*256*2);
  int* dsrc   = (int*)alloc((size_t)N_P2*4);
  int* ddst   = (int*)alloc((size_t)N_P2*4);
  int* cursor = (int*)alloc((size_t)N_P2*4);
  size_t zbytes = (size_t)(p - zbase);
  // ---- rest ----
  unsigned short* Hbuf0 = (unsigned short*)alloc((size_t)N_PAD*128*2);
  unsigned short* Hbuf1 = (unsigned short*)alloc((size_t)N_PAD*128*2);
  unsigned short* Xtr   = (unsigned short*)alloc((size_t)N_PAD*768*2);   // 2 halves x [n*64+d][6]
  unsigned short* U1tr  = (unsigned short*)alloc((size_t)N_PAD*768*2);
  unsigned short* Axt   = (unsigned short*)alloc((size_t)S_DIM*N_PAD*AXC*2);
  unsigned short* Bct   = (unsigned short*)alloc((size_t)N_COL*K_TOT*2);
  float*          btot  = (float*)alloc(N_COL*4);
  unsigned short* W1t   = (unsigned short*)alloc(HID_P*128*2);
  float*          b1p   = (float*)alloc(HID_P*4);
  float*          W2p   = (float*)alloc(HID_P*2*4);
  float*          dinv  = (float*)alloc((size_t)N_P2*4);
  int*            offs  = (int*)alloc((size_t)(N_P2+256)*4);
  int*            outp  = (int*)alloc((size_t)N_P2*4);
  int*            partb = (int*)alloc(256*4);
  int2*           cedge = (int2*)alloc((size_t)N_E*8);

  hipMemsetAsync(zbase, 0, zbytes, stream);
  k_setup<<<NB_PREP + NB_XPREP + NB_DEG, 256, 0, stream>>>(H, ei, Wx, Wh, bx, bh, bg,
      W1, b1, W2, Bct, btot, W1t, b1p, W2p, Xtr, Axt, dsrc, ddst);
  k_scan1d<<<N_P2/256, 256, 0, stream>>>(ddst, outp, partb, dsrc, dinv);
  k_scan3f<<<N_P2/256, 256, 0, stream>>>(outp, partb, offs);
  k_csr<<<NB_DEG, 256, 0, stream>>>(ei, dinv, offs, cursor, cedge);
  k_xspmm1<<<2*NB_SPMM, 256, 0, stream>>>(Xtr, Axt, U1tr, offs, cedge);
  k_xspmm2<<<2*NB_SPMM, 256, 0, stream>>>(U1tr, Axt, offs, cedge);

  // t = 0: h == 0 -> only x-part of K (it0 = 6); Hc/U never read (Ubuf pre-zeroed).
  k_gemm<<<dim3(4, N_PAD/128), 256, 0, stream>>>(Hbuf0, Ubuf, Axt,
      Bct, btot, wc, c_st, Hbuf1, 6);
  for (int t = 1; t < S_DIM; ++t){
    unsigned short* Hc = (t & 1) ? Hbuf1 : Hbuf0;
    unsigned short* Hn = (t & 1) ? Hbuf0 : Hbuf1;
    k_sp1ln<<<NB_SPMM + NB_LN, 256, 0, stream>>>(Hc, Ubuf, offs, cedge,
        W1t, b1p, W2p, b2, gam, bet, out, t-1);
    k_spmm2<<<NB_SPMM, 256, 0, stream>>>(Ubuf, offs, cedge);
    k_gemm<<<dim3(4, N_PAD/128), 256, 0, stream>>>(Hc, Ubuf,
        Axt + (size_t)t*N_PAD*AXC, Bct, btot, wc, c_st, Hn, 0);
  }
  k_lnmlp<<<NB_LN, 256, 0, stream>>>(Hbuf0, W1t, b1p, W2p, b2, gam, bet, out, 11);
}